// Round 1
// 938.336 us; speedup vs baseline: 1.0361x; 1.0361x over previous
//
#include <hip/hip_runtime.h>
#include <stdint.h>

// Problem constants (fixed by reference)
#define BB 8
#define NN 20000
#define CC 256
#define EE 320000
#define KK 3
#define MROWS (BB * NN)   // 160000
#define ROWU (BB * CC)    // 2048 ushorts per node-group (4 KB)

// ---------- bf16 helpers (raw ushort representation) ----------
__device__ __forceinline__ float bf2f(ushort u) {
    union { uint32_t ui; float f; } v; v.ui = ((uint32_t)u) << 16; return v.f;
}
__device__ __forceinline__ ushort f2bf(float f) {
    union { uint32_t ui; float f; } v; v.f = f;
    uint32_t r = (v.ui + 0x7FFFu + ((v.ui >> 16) & 1u)) >> 16;
    return (ushort)r;
}

typedef __bf16 bf16x8 __attribute__((ext_vector_type(8)));
typedef float  f32x4  __attribute__((ext_vector_type(4)));

__device__ __forceinline__ void gload16(const void* gptr, void* lptr) {
    __builtin_amdgcn_global_load_lds(
        (const __attribute__((address_space(1))) void*)gptr,
        (__attribute__((address_space(3))) void*)lptr, 16, 0, 0);
}

// ---------- edge width detect: int64 high words are all zero ----------
__global__ void detect_k(const int* __restrict__ raw, int* __restrict__ flag) {
    int i = blockIdx.x * 256 + threadIdx.x;
    int v = 0;
    int idx = 2 * i + 1;
    if (i < EE) v = raw[idx];            // odd 32-bit word in [0, 2E)
    unsigned long long m = __ballot(v != 0);
    if ((threadIdx.x & 63) == 0 && m) atomicOr(flag, 1);
}

// normalize edges to int32 src[]/dst[]
__global__ void convert_k(const int* __restrict__ raw, const int* __restrict__ flag,
                          int* __restrict__ src, int* __restrict__ dst) {
    int e = blockIdx.x * 256 + threadIdx.x;
    if (e >= EE) return;
    if (*flag == 0) {  // int64 (little-endian low words)
        src[e] = raw[2 * e];
        dst[e] = raw[2 * EE + 2 * e];
    } else {           // int32
        src[e] = raw[e];
        dst[e] = raw[EE + e];
    }
}

__global__ void count_k(const int* __restrict__ src, const int* __restrict__ dst,
                        int* __restrict__ deg_out, int* __restrict__ cnt_in) {
    int e = blockIdx.x * 256 + threadIdx.x;
    if (e >= EE) return;
    atomicAdd(&deg_out[src[e]], 1);
    atomicAdd(&cnt_in[dst[e]], 1);
}

// single-block scan, shfl-based: thread t owns 20 contiguous elements.
__global__ void __launch_bounds__(1024) scan_k(const int* __restrict__ cnt_in,
                                               const int* __restrict__ deg_out,
                                               int* __restrict__ row_ptr,
                                               float* __restrict__ dis) {
    __shared__ int wpart[16];
    const int t = threadIdx.x;
    const int lane = t & 63, wid = t >> 6;
    const int base = t * 20;
    int local[20];
    int sum = 0;
#pragma unroll
    for (int i = 0; i < 20; i++) {
        int idx = base + i;
        int v = (idx < NN) ? cnt_in[idx] : 0;
        local[i] = sum;
        sum += v;
    }
    int sc = sum;  // inclusive wave scan of per-thread sums
#pragma unroll
    for (int off = 1; off < 64; off <<= 1) {
        int u = __shfl_up(sc, off, 64);
        if (lane >= off) sc += u;
    }
    if (lane == 63) wpart[wid] = sc;
    __syncthreads();
    if (wid == 0 && lane < 16) {
        int v = wpart[lane];
#pragma unroll
        for (int off = 1; off < 16; off <<= 1) {
            int u = __shfl_up(v, off, 64);
            if (lane >= off) v += u;
        }
        wpart[lane] = v;
    }
    __syncthreads();
    int wbase = (wid > 0) ? wpart[wid - 1] : 0;
    int tbase = wbase + sc - sum;  // exclusive base for this thread
#pragma unroll
    for (int i = 0; i < 20; i++) {
        int idx = base + i;
        if (idx < NN) row_ptr[idx] = tbase + local[i];
    }
    if (t == 1023) row_ptr[NN] = tbase + sum;
    for (int i = t; i < NN; i += 1024) {
        int d = deg_out[i];
        dis[i] = (d > 0) ? rsqrtf((float)d) : 0.0f;
    }
}

__global__ void fill_k(const int* __restrict__ src, const int* __restrict__ dst,
                       const int* __restrict__ row_ptr, int* __restrict__ fillc,
                       const float* __restrict__ dis,
                       int* __restrict__ col, float* __restrict__ w) {
    int e = blockIdx.x * 256 + threadIdx.x;
    if (e >= EE) return;
    int s = src[e], d = dst[e];
    int pos = row_ptr[d] + atomicAdd(&fillc[d], 1);
    col[pos] = s;
    w[pos] = -dis[s] * dis[d];
}

// fp32 [b,n,c] -> bf16 node-major [n,b,c]
__global__ void cvt_k(const float* __restrict__ x, ushort* __restrict__ y) {
    size_t idx = ((size_t)blockIdx.x * 256 + threadIdx.x) * 4;
    int row = (int)(idx >> 8);     // b*N + n  (< 160000)
    int c = (int)(idx & 255);
    int b = row / NN, n = row - b * NN;
    float4 v = *(const float4*)(x + idx);
    ushort4 o = make_ushort4(f2bf(v.x), f2bf(v.y), f2bf(v.z), f2bf(v.w));
    *(ushort4*)(y + ((size_t)(n * BB + b) * CC + c)) = o;
}

// Build WcatT[n][k] bf16, n in [0,256), k in [0,768):
//   block 0: W1[0]-W1[2], block 1: W1[1], block 2: 2*W1[2]   (Tx2 = 2*P2 - Tx0 folded)
__global__ void wprep_k(const float* __restrict__ W, ushort* __restrict__ wt) {
    int idx = blockIdx.x * 256 + threadIdx.x;
    if (idx >= 256 * 768) return;
    int n = idx / 768, k = idx % 768;
    int sel = k >> 8, kk = k & 255;
    const float* W1 = W + KK * CC * CC;  // layer 1
    float v;
    if (sel == 0)      v = W1[kk * CC + n] - W1[2 * CC * CC + kk * CC + n];
    else if (sel == 1) v = W1[CC * CC + kk * CC + n];
    else               v = 2.0f * W1[2 * CC * CC + kk * CC + n];
    wt[idx] = f2bf(v);
}

// Node-major prop: y[n, :, :] = sum_{e: dst=n} w[e] * x[col[e], :, :]
// one 256-thread block per dst node; thread t covers bytes [t*16, t*16+16)
// of the 4 KB node-group. Edge loop unrolled by 4 for MLP.
__global__ void __launch_bounds__(256) prop_k(const ushort* __restrict__ x,
                                              ushort* __restrict__ y,
                                              const int* __restrict__ row_ptr,
                                              const int* __restrict__ col,
                                              const float* __restrict__ w) {
    const int n = blockIdx.x;
    const int t = threadIdx.x;
    const int beg = row_ptr[n], end = row_ptr[n + 1];
    const ushort* xb = x + t * 8;   // 8 ushorts = 16 B per thread
    float a0 = 0, a1 = 0, a2 = 0, a3 = 0, a4 = 0, a5 = 0, a6 = 0, a7 = 0;
    int j = beg;
    for (; j + 4 <= end; j += 4) {
        int s0 = col[j], s1 = col[j + 1], s2 = col[j + 2], s3 = col[j + 3];
        float w0 = w[j], w1 = w[j + 1], w2 = w[j + 2], w3 = w[j + 3];
        uint4 v0 = *(const uint4*)(xb + (size_t)s0 * ROWU);
        uint4 v1 = *(const uint4*)(xb + (size_t)s1 * ROWU);
        uint4 v2 = *(const uint4*)(xb + (size_t)s2 * ROWU);
        uint4 v3 = *(const uint4*)(xb + (size_t)s3 * ROWU);
        a0 += w0 * bf2f((ushort)v0.x) + w1 * bf2f((ushort)v1.x) + w2 * bf2f((ushort)v2.x) + w3 * bf2f((ushort)v3.x);
        a1 += w0 * bf2f((ushort)(v0.x >> 16)) + w1 * bf2f((ushort)(v1.x >> 16)) + w2 * bf2f((ushort)(v2.x >> 16)) + w3 * bf2f((ushort)(v3.x >> 16));
        a2 += w0 * bf2f((ushort)v0.y) + w1 * bf2f((ushort)v1.y) + w2 * bf2f((ushort)v2.y) + w3 * bf2f((ushort)v3.y);
        a3 += w0 * bf2f((ushort)(v0.y >> 16)) + w1 * bf2f((ushort)(v1.y >> 16)) + w2 * bf2f((ushort)(v2.y >> 16)) + w3 * bf2f((ushort)(v3.y >> 16));
        a4 += w0 * bf2f((ushort)v0.z) + w1 * bf2f((ushort)v1.z) + w2 * bf2f((ushort)v2.z) + w3 * bf2f((ushort)v3.z);
        a5 += w0 * bf2f((ushort)(v0.z >> 16)) + w1 * bf2f((ushort)(v1.z >> 16)) + w2 * bf2f((ushort)(v2.z >> 16)) + w3 * bf2f((ushort)(v3.z >> 16));
        a6 += w0 * bf2f((ushort)v0.w) + w1 * bf2f((ushort)v1.w) + w2 * bf2f((ushort)v2.w) + w3 * bf2f((ushort)v3.w);
        a7 += w0 * bf2f((ushort)(v0.w >> 16)) + w1 * bf2f((ushort)(v1.w >> 16)) + w2 * bf2f((ushort)(v2.w >> 16)) + w3 * bf2f((ushort)(v3.w >> 16));
    }
    for (; j < end; j++) {
        int s = col[j];
        float wt = w[j];
        uint4 v = *(const uint4*)(xb + (size_t)s * ROWU);
        a0 += wt * bf2f((ushort)v.x);
        a1 += wt * bf2f((ushort)(v.x >> 16));
        a2 += wt * bf2f((ushort)v.y);
        a3 += wt * bf2f((ushort)(v.y >> 16));
        a4 += wt * bf2f((ushort)v.z);
        a5 += wt * bf2f((ushort)(v.z >> 16));
        a6 += wt * bf2f((ushort)v.w);
        a7 += wt * bf2f((ushort)(v.w >> 16));
    }
    uint4 o;
    o.x = (uint32_t)f2bf(a0) | ((uint32_t)f2bf(a1) << 16);
    o.y = (uint32_t)f2bf(a2) | ((uint32_t)f2bf(a3) << 16);
    o.z = (uint32_t)f2bf(a4) | ((uint32_t)f2bf(a5) << 16);
    o.w = (uint32_t)f2bf(a6) | ((uint32_t)f2bf(a7) << 16);
    *(uint4*)(y + (size_t)n * ROWU + t * 8) = o;
}

// Fused GEMM + bias + LayerNorm.
// out = [A0|A1|A2] (bf16, node-major rows m'=n*8+b) @ WcatT^T, then per-row LN,
// with row un-permutation (m' -> b*N+n) in the epilogue.
// Tile: 64 rows x 256 cols (FULL C width -> row stats computable in-block),
// BK=32, 256 threads, 4 waves in 1x4 layout (each wave 64x64 via 4x4 mfma 16x16x32).
// A is fetched exactly ONCE (vs twice with 128-col tiles); ln_k pass eliminated.
__global__ void __launch_bounds__(256) gemmln_k(const ushort* __restrict__ a0,
                                                const ushort* __restrict__ a1,
                                                const ushort* __restrict__ a2,
                                                const ushort* __restrict__ wt,
                                                const float* __restrict__ bias,
                                                const float* __restrict__ lnw,
                                                const float* __restrict__ lnb,
                                                float* __restrict__ out) {
    __shared__ ushort As[64 * 32];    // 4 KB
    __shared__ ushort Bs[256 * 32];   // 16 KB
    __shared__ float reds[64][4];     // per-row per-wave partial sum
    __shared__ float redq[64][4];     // per-row per-wave partial sumsq
    const int tid = threadIdx.x;
    const int wid = tid >> 6, lane = tid & 63;
    const int quad = lane >> 4, l16 = lane & 15;
    const int row0 = blockIdx.x * 64;

    f32x4 acc[4][4] = {};

    for (int kt = 0; kt < 24; kt++) {
        const ushort* ab = (kt < 8) ? a0 : ((kt < 16) ? a1 : a2);
        const int kl = (kt & 7) * 32;        // k offset within the 256-col buffer
        const int kg = kt * 32;              // global k for WcatT
        __syncthreads();
        // stage A: 64x32 bf16 = 4 KB = 256 x 16B chunks; chunk c = wid*64+lane
        {
            int c = wid * 64 + lane;
            int m = c >> 2, kq = (c & 3) * 8;
            gload16(ab + (size_t)(row0 + m) * CC + kl + kq, &As[(wid * 64) * 8]);
        }
        // stage B: 256x32 bf16 = 16 KB = 1024 chunks; c = wid*256 + q*64 + lane
#pragma unroll
        for (int q = 0; q < 4; q++) {
            int c = wid * 256 + q * 64 + lane;
            int m = c >> 2, kq = (c & 3) * 8;
            gload16(wt + (size_t)m * 768 + kg + kq, &Bs[(wid * 256 + q * 64) * 8]);
        }
        __syncthreads();

        bf16x8 af[4], bfr[4];
#pragma unroll
        for (int mt = 0; mt < 4; mt++)
            af[mt] = *(const bf16x8*)&As[(mt * 16 + l16) * 32 + quad * 8];
#pragma unroll
        for (int nt = 0; nt < 4; nt++)
            bfr[nt] = *(const bf16x8*)&Bs[(wid * 64 + nt * 16 + l16) * 32 + quad * 8];
#pragma unroll
        for (int mt = 0; mt < 4; mt++)
#pragma unroll
            for (int nt = 0; nt < 4; nt++)
                acc[mt][nt] = __builtin_amdgcn_mfma_f32_16x16x32_bf16(
                    af[mt], bfr[nt], acc[mt][nt], 0, 0, 0);
    }

    // ---- fused epilogue: bias + LayerNorm + un-permute + store ----
    // C/D layout: col = lane&15, row = (lane>>4)*4 + reg   [measured m89]
    // lane's cols: wid*64 + nt*16 + l16, nt=0..3
    float bv[4], lwv[4], lbv[4];
#pragma unroll
    for (int nt = 0; nt < 4; nt++) {
        int c = wid * 64 + nt * 16 + l16;
        bv[nt] = bias[c]; lwv[nt] = lnw[c]; lbv[nt] = lnb[c];
    }
    // per-row partial stats over this wave's 64 cols (reduce over l16 group)
#pragma unroll
    for (int mt = 0; mt < 4; mt++) {
#pragma unroll
        for (int r = 0; r < 4; r++) {
            float s = 0.0f, q = 0.0f;
#pragma unroll
            for (int nt = 0; nt < 4; nt++) {
                float v = acc[mt][nt][r] + bv[nt];
                s += v; q += v * v;
            }
#pragma unroll
            for (int off = 1; off < 16; off <<= 1) {
                s += __shfl_xor(s, off, 64);
                q += __shfl_xor(q, off, 64);
            }
            if (l16 == 0) {
                int m = mt * 16 + quad * 4 + r;
                reds[m][wid] = s;
                redq[m][wid] = q;
            }
        }
    }
    __syncthreads();
#pragma unroll
    for (int mt = 0; mt < 4; mt++) {
#pragma unroll
        for (int r = 0; r < 4; r++) {
            int ml = mt * 16 + quad * 4 + r;
            float s = reds[ml][0] + reds[ml][1] + reds[ml][2] + reds[ml][3];
            float q = redq[ml][0] + redq[ml][1] + redq[ml][2] + redq[ml][3];
            float mean = s * (1.0f / CC);
            float var = q * (1.0f / CC) - mean * mean;
            float rs = rsqrtf(var + 1e-5f);
            int m = row0 + ml;
            int n = m >> 3, b = m & 7;
            size_t orow = (size_t)b * NN + n;
#pragma unroll
            for (int nt = 0; nt < 4; nt++) {
                int c = wid * 64 + nt * 16 + l16;
                float v = (acc[mt][nt][r] + bv[nt] - mean) * rs * lwv[nt] + lbv[nt];
                out[orow * CC + c] = v;
            }
        }
    }
}

extern "C" void kernel_launch(void* const* d_in, const int* in_sizes, int n_in,
                              void* d_out, int out_size, void* d_ws, size_t ws_size,
                              hipStream_t stream) {
    const float* feats = (const float*)d_in[0];
    const float* W     = (const float*)d_in[1];   // [L,K,C,C]
    const float* bvec  = (const float*)d_in[2];   // [L,C]
    const float* lnw   = (const float*)d_in[3];   // [L,C]
    const float* lnb   = (const float*)d_in[4];   // [L,C]
    const int*   eidx  = (const int*)d_in[5];     // (2,E) int32 or int64 (detected)
    float* outp = (float*)d_out;

    // ---- workspace carve-up ----
    int* flag    = (int*)d_ws;            // 64 ints (only [0] used)
    int* deg_out = flag + 64;             // N
    int* cnt_in  = deg_out + NN;          // N
    int* fillc   = cnt_in + NN;           // N   (memset covers up to here)
    int* row_ptr = fillc + NN;            // N+1 (+pad)
    int* srcw    = row_ptr + (NN + 64);   // E
    int* dstw    = srcw + EE;             // E
    int* colw    = dstw + EE;             // E
    float* disw  = (float*)(colw + EE);   // N (+pad)
    float* ww    = disw + (NN + 64);      // E
    uintptr_t bf_base = ((uintptr_t)(ww + EE) + 255) & ~(uintptr_t)255;
    ushort* featsb = (ushort*)bf_base;                 // M*C bf16  [n,b,c]
    ushort* tx1b   = featsb + (size_t)MROWS * CC;      // M*C
    ushort* p2b    = tx1b + (size_t)MROWS * CC;        // M*C
    ushort* wcat   = p2b + (size_t)MROWS * CC;         // 256*768

    hipMemsetAsync(flag, 0, (size_t)(64 + 3 * NN) * sizeof(int), stream);

    int eb = (EE + 255) / 256;  // 1250
    detect_k<<<eb, 256, 0, stream>>>(eidx, flag);
    convert_k<<<eb, 256, 0, stream>>>(eidx, flag, srcw, dstw);
    count_k<<<eb, 256, 0, stream>>>(srcw, dstw, deg_out, cnt_in);
    scan_k<<<1, 1024, 0, stream>>>(cnt_in, deg_out, row_ptr, disw);
    fill_k<<<eb, 256, 0, stream>>>(srcw, dstw, row_ptr, fillc, disw, colw, ww);

    cvt_k<<<MROWS * CC / 1024, 256, 0, stream>>>(feats, featsb);     // 40000 blocks
    wprep_k<<<(256 * 768 + 255) / 256, 256, 0, stream>>>(W, wcat);   // 768 blocks

    prop_k<<<NN, 256, 0, stream>>>(featsb, tx1b, row_ptr, colw, ww);
    prop_k<<<NN, 256, 0, stream>>>(tx1b, p2b, row_ptr, colw, ww);

    // fused GEMM + bias + LayerNorm (layer-1 params; layer-0 output is overwritten)
    gemmln_k<<<MROWS / 64, 256, 0, stream>>>(featsb, tx1b, p2b, wcat,
                                             bvec + CC, lnw + CC, lnb + CC, outp);
}

// Round 2
// 914.507 us; speedup vs baseline: 1.0631x; 1.0261x over previous
//
#include <hip/hip_runtime.h>
#include <stdint.h>

// Problem constants (fixed by reference)
#define BB 8
#define NN 20000
#define CC 256
#define EE 320000
#define KK 3
#define MROWS (BB * NN)   // 160000
#define ROWU (BB * CC)    // 2048 ushorts per node-group (4 KB)

// ---------- bf16 helpers (raw ushort representation) ----------
__device__ __forceinline__ float bf2f(ushort u) {
    union { uint32_t ui; float f; } v; v.ui = ((uint32_t)u) << 16; return v.f;
}
__device__ __forceinline__ ushort f2bf(float f) {
    union { uint32_t ui; float f; } v; v.f = f;
    uint32_t r = (v.ui + 0x7FFFu + ((v.ui >> 16) & 1u)) >> 16;
    return (ushort)r;
}

typedef __bf16 bf16x8 __attribute__((ext_vector_type(8)));
typedef float  f32x4  __attribute__((ext_vector_type(4)));

__device__ __forceinline__ void gload16(const void* gptr, void* lptr) {
    __builtin_amdgcn_global_load_lds(
        (const __attribute__((address_space(1))) void*)gptr,
        (__attribute__((address_space(3))) void*)lptr, 16, 0, 0);
}

// ---------- edge width detect: int64 high words are all zero ----------
__global__ void detect_k(const int* __restrict__ raw, int* __restrict__ flag) {
    int i = blockIdx.x * 256 + threadIdx.x;
    int v = 0;
    int idx = 2 * i + 1;
    if (i < EE) v = raw[idx];            // odd 32-bit word in [0, 2E)
    unsigned long long m = __ballot(v != 0);
    if ((threadIdx.x & 63) == 0 && m) atomicOr(flag, 1);
}

// normalize edges to int32 src[]/dst[]
__global__ void convert_k(const int* __restrict__ raw, const int* __restrict__ flag,
                          int* __restrict__ src, int* __restrict__ dst) {
    int e = blockIdx.x * 256 + threadIdx.x;
    if (e >= EE) return;
    if (*flag == 0) {  // int64 (little-endian low words)
        src[e] = raw[2 * e];
        dst[e] = raw[2 * EE + 2 * e];
    } else {           // int32
        src[e] = raw[e];
        dst[e] = raw[EE + e];
    }
}

__global__ void count_k(const int* __restrict__ src, const int* __restrict__ dst,
                        int* __restrict__ deg_out, int* __restrict__ cnt_in) {
    int e = blockIdx.x * 256 + threadIdx.x;
    if (e >= EE) return;
    atomicAdd(&deg_out[src[e]], 1);
    atomicAdd(&cnt_in[dst[e]], 1);
}

// single-block scan, shfl-based: thread t owns 20 contiguous elements.
__global__ void __launch_bounds__(1024) scan_k(const int* __restrict__ cnt_in,
                                               const int* __restrict__ deg_out,
                                               int* __restrict__ row_ptr,
                                               float* __restrict__ dis) {
    __shared__ int wpart[16];
    const int t = threadIdx.x;
    const int lane = t & 63, wid = t >> 6;
    const int base = t * 20;
    int local[20];
    int sum = 0;
#pragma unroll
    for (int i = 0; i < 20; i++) {
        int idx = base + i;
        int v = (idx < NN) ? cnt_in[idx] : 0;
        local[i] = sum;
        sum += v;
    }
    int sc = sum;  // inclusive wave scan of per-thread sums
#pragma unroll
    for (int off = 1; off < 64; off <<= 1) {
        int u = __shfl_up(sc, off, 64);
        if (lane >= off) sc += u;
    }
    if (lane == 63) wpart[wid] = sc;
    __syncthreads();
    if (wid == 0 && lane < 16) {
        int v = wpart[lane];
#pragma unroll
        for (int off = 1; off < 16; off <<= 1) {
            int u = __shfl_up(v, off, 64);
            if (lane >= off) v += u;
        }
        wpart[lane] = v;
    }
    __syncthreads();
    int wbase = (wid > 0) ? wpart[wid - 1] : 0;
    int tbase = wbase + sc - sum;  // exclusive base for this thread
#pragma unroll
    for (int i = 0; i < 20; i++) {
        int idx = base + i;
        if (idx < NN) row_ptr[idx] = tbase + local[i];
    }
    if (t == 1023) row_ptr[NN] = tbase + sum;
    for (int i = t; i < NN; i += 1024) {
        int d = deg_out[i];
        dis[i] = (d > 0) ? rsqrtf((float)d) : 0.0f;
    }
}

__global__ void fill_k(const int* __restrict__ src, const int* __restrict__ dst,
                       const int* __restrict__ row_ptr, int* __restrict__ fillc,
                       const float* __restrict__ dis,
                       int* __restrict__ col, float* __restrict__ w) {
    int e = blockIdx.x * 256 + threadIdx.x;
    if (e >= EE) return;
    int s = src[e], d = dst[e];
    int pos = row_ptr[d] + atomicAdd(&fillc[d], 1);
    col[pos] = s;
    w[pos] = -dis[s] * dis[d];
}

// fp32 [b,n,c] -> bf16 node-major [n,b,c]
__global__ void cvt_k(const float* __restrict__ x, ushort* __restrict__ y) {
    size_t idx = ((size_t)blockIdx.x * 256 + threadIdx.x) * 4;
    int row = (int)(idx >> 8);     // b*N + n  (< 160000)
    int c = (int)(idx & 255);
    int b = row / NN, n = row - b * NN;
    float4 v = *(const float4*)(x + idx);
    ushort4 o = make_ushort4(f2bf(v.x), f2bf(v.y), f2bf(v.z), f2bf(v.w));
    *(ushort4*)(y + ((size_t)(n * BB + b) * CC + c)) = o;
}

// Build WcatT[n][k] bf16, n in [0,256), k in [0,768):
//   block 0: W1[0]-W1[2], block 1: W1[1], block 2: 2*W1[2]   (Tx2 = 2*P2 - Tx0 folded)
__global__ void wprep_k(const float* __restrict__ W, ushort* __restrict__ wt) {
    int idx = blockIdx.x * 256 + threadIdx.x;
    if (idx >= 256 * 768) return;
    int n = idx / 768, k = idx % 768;
    int sel = k >> 8, kk = k & 255;
    const float* W1 = W + KK * CC * CC;  // layer 1
    float v;
    if (sel == 0)      v = W1[kk * CC + n] - W1[2 * CC * CC + kk * CC + n];
    else if (sel == 1) v = W1[CC * CC + kk * CC + n];
    else               v = 2.0f * W1[2 * CC * CC + kk * CC + n];
    wt[idx] = f2bf(v);
}

// Node-major prop: y[n, :, :] = sum_{e: dst=n} w[e] * x[col[e], :, :]
// one 256-thread block per dst node; thread t covers bytes [t*16, t*16+16)
// of the 4 KB node-group. Edge loop unrolled by 8 for MLP (latency-bound gather:
// 45% HBM peak @ unroll-4, VALUBusy 17% -> double outstanding loads).
__global__ void __launch_bounds__(256) prop_k(const ushort* __restrict__ x,
                                              ushort* __restrict__ y,
                                              const int* __restrict__ row_ptr,
                                              const int* __restrict__ col,
                                              const float* __restrict__ w) {
    const int n = blockIdx.x;
    const int t = threadIdx.x;
    const int beg = row_ptr[n], end = row_ptr[n + 1];
    const ushort* xb = x + t * 8;   // 8 ushorts = 16 B per thread
    float a0 = 0, a1 = 0, a2 = 0, a3 = 0, a4 = 0, a5 = 0, a6 = 0, a7 = 0;
    int j = beg;
    for (; j + 8 <= end; j += 8) {
        int s0 = col[j], s1 = col[j + 1], s2 = col[j + 2], s3 = col[j + 3];
        int s4 = col[j + 4], s5 = col[j + 5], s6 = col[j + 6], s7 = col[j + 7];
        float w0 = w[j], w1 = w[j + 1], w2 = w[j + 2], w3 = w[j + 3];
        float w4 = w[j + 4], w5 = w[j + 5], w6 = w[j + 6], w7 = w[j + 7];
        uint4 v0 = *(const uint4*)(xb + (size_t)s0 * ROWU);
        uint4 v1 = *(const uint4*)(xb + (size_t)s1 * ROWU);
        uint4 v2 = *(const uint4*)(xb + (size_t)s2 * ROWU);
        uint4 v3 = *(const uint4*)(xb + (size_t)s3 * ROWU);
        uint4 v4 = *(const uint4*)(xb + (size_t)s4 * ROWU);
        uint4 v5 = *(const uint4*)(xb + (size_t)s5 * ROWU);
        uint4 v6 = *(const uint4*)(xb + (size_t)s6 * ROWU);
        uint4 v7 = *(const uint4*)(xb + (size_t)s7 * ROWU);
        a0 += ((w0 * bf2f((ushort)v0.x) + w1 * bf2f((ushort)v1.x)) + (w2 * bf2f((ushort)v2.x) + w3 * bf2f((ushort)v3.x)))
            + ((w4 * bf2f((ushort)v4.x) + w5 * bf2f((ushort)v5.x)) + (w6 * bf2f((ushort)v6.x) + w7 * bf2f((ushort)v7.x)));
        a1 += ((w0 * bf2f((ushort)(v0.x >> 16)) + w1 * bf2f((ushort)(v1.x >> 16))) + (w2 * bf2f((ushort)(v2.x >> 16)) + w3 * bf2f((ushort)(v3.x >> 16))))
            + ((w4 * bf2f((ushort)(v4.x >> 16)) + w5 * bf2f((ushort)(v5.x >> 16))) + (w6 * bf2f((ushort)(v6.x >> 16)) + w7 * bf2f((ushort)(v7.x >> 16))));
        a2 += ((w0 * bf2f((ushort)v0.y) + w1 * bf2f((ushort)v1.y)) + (w2 * bf2f((ushort)v2.y) + w3 * bf2f((ushort)v3.y)))
            + ((w4 * bf2f((ushort)v4.y) + w5 * bf2f((ushort)v5.y)) + (w6 * bf2f((ushort)v6.y) + w7 * bf2f((ushort)v7.y)));
        a3 += ((w0 * bf2f((ushort)(v0.y >> 16)) + w1 * bf2f((ushort)(v1.y >> 16))) + (w2 * bf2f((ushort)(v2.y >> 16)) + w3 * bf2f((ushort)(v3.y >> 16))))
            + ((w4 * bf2f((ushort)(v4.y >> 16)) + w5 * bf2f((ushort)(v5.y >> 16))) + (w6 * bf2f((ushort)(v6.y >> 16)) + w7 * bf2f((ushort)(v7.y >> 16))));
        a4 += ((w0 * bf2f((ushort)v0.z) + w1 * bf2f((ushort)v1.z)) + (w2 * bf2f((ushort)v2.z) + w3 * bf2f((ushort)v3.z)))
            + ((w4 * bf2f((ushort)v4.z) + w5 * bf2f((ushort)v5.z)) + (w6 * bf2f((ushort)v6.z) + w7 * bf2f((ushort)v7.z)));
        a5 += ((w0 * bf2f((ushort)(v0.z >> 16)) + w1 * bf2f((ushort)(v1.z >> 16))) + (w2 * bf2f((ushort)(v2.z >> 16)) + w3 * bf2f((ushort)(v3.z >> 16))))
            + ((w4 * bf2f((ushort)(v4.z >> 16)) + w5 * bf2f((ushort)(v5.z >> 16))) + (w6 * bf2f((ushort)(v6.z >> 16)) + w7 * bf2f((ushort)(v7.z >> 16))));
        a6 += ((w0 * bf2f((ushort)v0.w) + w1 * bf2f((ushort)v1.w)) + (w2 * bf2f((ushort)v2.w) + w3 * bf2f((ushort)v3.w)))
            + ((w4 * bf2f((ushort)v4.w) + w5 * bf2f((ushort)v5.w)) + (w6 * bf2f((ushort)v6.w) + w7 * bf2f((ushort)v7.w)));
        a7 += ((w0 * bf2f((ushort)(v0.w >> 16)) + w1 * bf2f((ushort)(v1.w >> 16))) + (w2 * bf2f((ushort)(v2.w >> 16)) + w3 * bf2f((ushort)(v3.w >> 16))))
            + ((w4 * bf2f((ushort)(v4.w >> 16)) + w5 * bf2f((ushort)(v5.w >> 16))) + (w6 * bf2f((ushort)(v6.w >> 16)) + w7 * bf2f((ushort)(v7.w >> 16))));
    }
    for (; j + 4 <= end; j += 4) {
        int s0 = col[j], s1 = col[j + 1], s2 = col[j + 2], s3 = col[j + 3];
        float w0 = w[j], w1 = w[j + 1], w2 = w[j + 2], w3 = w[j + 3];
        uint4 v0 = *(const uint4*)(xb + (size_t)s0 * ROWU);
        uint4 v1 = *(const uint4*)(xb + (size_t)s1 * ROWU);
        uint4 v2 = *(const uint4*)(xb + (size_t)s2 * ROWU);
        uint4 v3 = *(const uint4*)(xb + (size_t)s3 * ROWU);
        a0 += (w0 * bf2f((ushort)v0.x) + w1 * bf2f((ushort)v1.x)) + (w2 * bf2f((ushort)v2.x) + w3 * bf2f((ushort)v3.x));
        a1 += (w0 * bf2f((ushort)(v0.x >> 16)) + w1 * bf2f((ushort)(v1.x >> 16))) + (w2 * bf2f((ushort)(v2.x >> 16)) + w3 * bf2f((ushort)(v3.x >> 16)));
        a2 += (w0 * bf2f((ushort)v0.y) + w1 * bf2f((ushort)v1.y)) + (w2 * bf2f((ushort)v2.y) + w3 * bf2f((ushort)v3.y));
        a3 += (w0 * bf2f((ushort)(v0.y >> 16)) + w1 * bf2f((ushort)(v1.y >> 16))) + (w2 * bf2f((ushort)(v2.y >> 16)) + w3 * bf2f((ushort)(v3.y >> 16)));
        a4 += (w0 * bf2f((ushort)v0.z) + w1 * bf2f((ushort)v1.z)) + (w2 * bf2f((ushort)v2.z) + w3 * bf2f((ushort)v3.z));
        a5 += (w0 * bf2f((ushort)(v0.z >> 16)) + w1 * bf2f((ushort)(v1.z >> 16))) + (w2 * bf2f((ushort)(v2.z >> 16)) + w3 * bf2f((ushort)(v3.z >> 16)));
        a6 += (w0 * bf2f((ushort)v0.w) + w1 * bf2f((ushort)v1.w)) + (w2 * bf2f((ushort)v2.w) + w3 * bf2f((ushort)v3.w));
        a7 += (w0 * bf2f((ushort)(v0.w >> 16)) + w1 * bf2f((ushort)(v1.w >> 16))) + (w2 * bf2f((ushort)(v2.w >> 16)) + w3 * bf2f((ushort)(v3.w >> 16)));
    }
    for (; j < end; j++) {
        int s = col[j];
        float wt = w[j];
        uint4 v = *(const uint4*)(xb + (size_t)s * ROWU);
        a0 += wt * bf2f((ushort)v.x);
        a1 += wt * bf2f((ushort)(v.x >> 16));
        a2 += wt * bf2f((ushort)v.y);
        a3 += wt * bf2f((ushort)(v.y >> 16));
        a4 += wt * bf2f((ushort)v.z);
        a5 += wt * bf2f((ushort)(v.z >> 16));
        a6 += wt * bf2f((ushort)v.w);
        a7 += wt * bf2f((ushort)(v.w >> 16));
    }
    uint4 o;
    o.x = (uint32_t)f2bf(a0) | ((uint32_t)f2bf(a1) << 16);
    o.y = (uint32_t)f2bf(a2) | ((uint32_t)f2bf(a3) << 16);
    o.z = (uint32_t)f2bf(a4) | ((uint32_t)f2bf(a5) << 16);
    o.w = (uint32_t)f2bf(a6) | ((uint32_t)f2bf(a7) << 16);
    *(uint4*)(y + (size_t)n * ROWU + t * 8) = o;
}

// Fused GEMM + bias + LayerNorm.
// out = [A0|A1|A2] (bf16, node-major rows m'=n*8+b) @ WcatT^T, then per-row LN,
// with row un-permutation (m' -> b*N+n) in the epilogue.
// Tile: 128 rows x 256 cols (full C width -> row stats in-block), BK=32,
// 512 threads = 8 waves (2 row-groups x 4 col-groups), wave tile 64x64 (4x4 mfma).
// m97-class inner loop: per wave per kt = 3 gload16/thread + 8 ds_read_b128 + 16 MFMA.
// __launch_bounds__(512,4) caps VGPR at 128 -> 2 blocks (16 waves)/CU so the
// per-kt vmcnt(0)+barrier drain overlaps with the other block's compute.
__global__ void __launch_bounds__(512, 4) gemmln_k(const ushort* __restrict__ a0,
                                                   const ushort* __restrict__ a1,
                                                   const ushort* __restrict__ a2,
                                                   const ushort* __restrict__ wt,
                                                   const float* __restrict__ bias,
                                                   const float* __restrict__ lnw,
                                                   const float* __restrict__ lnb,
                                                   float* __restrict__ out) {
    __shared__ ushort As[128 * 32];   // 8 KB
    __shared__ ushort Bs[256 * 32];   // 16 KB
    __shared__ float reds[128][4];    // per-row per-colwave partial sum
    __shared__ float redq[128][4];    // per-row per-colwave partial sumsq
    const int tid = threadIdx.x;
    const int wid = tid >> 6, lane = tid & 63;
    const int wrow = wid >> 2, wcol = wid & 3;
    const int quad = lane >> 4, l16 = lane & 15;
    const int row0 = blockIdx.x * 128;

    f32x4 acc[4][4] = {};

    for (int kt = 0; kt < 24; kt++) {
        const ushort* ab = (kt < 8) ? a0 : ((kt < 16) ? a1 : a2);
        const int kl = (kt & 7) * 32;        // k offset within the 256-col buffer
        const int kg = kt * 32;              // global k for WcatT
        __syncthreads();
        // stage A: 128x32 bf16 = 8 KB = 512 x 16B chunks; chunk c = tid
        {
            int m = tid >> 2, kq = (tid & 3) * 8;
            gload16(ab + (size_t)(row0 + m) * CC + kl + kq, &As[(wid * 64) * 8]);
        }
        // stage B: 256x32 bf16 = 16 KB = 1024 chunks; c = q*512 + tid
#pragma unroll
        for (int q = 0; q < 2; q++) {
            int c = q * 512 + tid;
            int m = c >> 2, kq = (c & 3) * 8;
            gload16(wt + (size_t)m * 768 + kg + kq, &Bs[(q * 512 + wid * 64) * 8]);
        }
        __syncthreads();

        bf16x8 af[4], bfr[4];
#pragma unroll
        for (int mt = 0; mt < 4; mt++)
            af[mt] = *(const bf16x8*)&As[(wrow * 64 + mt * 16 + l16) * 32 + quad * 8];
#pragma unroll
        for (int nt = 0; nt < 4; nt++)
            bfr[nt] = *(const bf16x8*)&Bs[(wcol * 64 + nt * 16 + l16) * 32 + quad * 8];
#pragma unroll
        for (int mt = 0; mt < 4; mt++)
#pragma unroll
            for (int nt = 0; nt < 4; nt++)
                acc[mt][nt] = __builtin_amdgcn_mfma_f32_16x16x32_bf16(
                    af[mt], bfr[nt], acc[mt][nt], 0, 0, 0);
    }

    // ---- fused epilogue: bias + LayerNorm + un-permute + store ----
    // C/D layout: col = lane&15, row = (lane>>4)*4 + reg   [measured m89]
    // lane's cols: wcol*64 + nt*16 + l16, nt=0..3
    float bv[4], lwv[4], lbv[4];
#pragma unroll
    for (int nt = 0; nt < 4; nt++) {
        int c = wcol * 64 + nt * 16 + l16;
        bv[nt] = bias[c]; lwv[nt] = lnw[c]; lbv[nt] = lnb[c];
    }
    // per-row partial stats over this wave's 64 cols (reduce over l16 group)
#pragma unroll
    for (int mt = 0; mt < 4; mt++) {
#pragma unroll
        for (int r = 0; r < 4; r++) {
            float s = 0.0f, q = 0.0f;
#pragma unroll
            for (int nt = 0; nt < 4; nt++) {
                float v = acc[mt][nt][r] + bv[nt];
                s += v; q += v * v;
            }
#pragma unroll
            for (int off = 1; off < 16; off <<= 1) {
                s += __shfl_xor(s, off, 64);
                q += __shfl_xor(q, off, 64);
            }
            if (l16 == 0) {
                int ml = wrow * 64 + mt * 16 + quad * 4 + r;
                reds[ml][wcol] = s;
                redq[ml][wcol] = q;
            }
        }
    }
    __syncthreads();
#pragma unroll
    for (int mt = 0; mt < 4; mt++) {
#pragma unroll
        for (int r = 0; r < 4; r++) {
            int ml = wrow * 64 + mt * 16 + quad * 4 + r;
            float s = reds[ml][0] + reds[ml][1] + reds[ml][2] + reds[ml][3];
            float q = redq[ml][0] + redq[ml][1] + redq[ml][2] + redq[ml][3];
            float mean = s * (1.0f / CC);
            float var = q * (1.0f / CC) - mean * mean;
            float rs = rsqrtf(var + 1e-5f);
            int m = row0 + ml;
            int n = m >> 3, b = m & 7;
            size_t orow = (size_t)b * NN + n;
#pragma unroll
            for (int nt = 0; nt < 4; nt++) {
                int c = wcol * 64 + nt * 16 + l16;
                float v = (acc[mt][nt][r] + bv[nt] - mean) * rs * lwv[nt] + lbv[nt];
                out[orow * CC + c] = v;
            }
        }
    }
}

extern "C" void kernel_launch(void* const* d_in, const int* in_sizes, int n_in,
                              void* d_out, int out_size, void* d_ws, size_t ws_size,
                              hipStream_t stream) {
    const float* feats = (const float*)d_in[0];
    const float* W     = (const float*)d_in[1];   // [L,K,C,C]
    const float* bvec  = (const float*)d_in[2];   // [L,C]
    const float* lnw   = (const float*)d_in[3];   // [L,C]
    const float* lnb   = (const float*)d_in[4];   // [L,C]
    const int*   eidx  = (const int*)d_in[5];     // (2,E) int32 or int64 (detected)
    float* outp = (float*)d_out;

    // ---- workspace carve-up ----
    int* flag    = (int*)d_ws;            // 64 ints (only [0] used)
    int* deg_out = flag + 64;             // N
    int* cnt_in  = deg_out + NN;          // N
    int* fillc   = cnt_in + NN;           // N   (memset covers up to here)
    int* row_ptr = fillc + NN;            // N+1 (+pad)
    int* srcw    = row_ptr + (NN + 64);   // E
    int* dstw    = srcw + EE;             // E
    int* colw    = dstw + EE;             // E
    float* disw  = (float*)(colw + EE);   // N (+pad)
    float* ww    = disw + (NN + 64);      // E
    uintptr_t bf_base = ((uintptr_t)(ww + EE) + 255) & ~(uintptr_t)255;
    ushort* featsb = (ushort*)bf_base;                 // M*C bf16  [n,b,c]
    ushort* tx1b   = featsb + (size_t)MROWS * CC;      // M*C
    ushort* p2b    = tx1b + (size_t)MROWS * CC;        // M*C
    ushort* wcat   = p2b + (size_t)MROWS * CC;         // 256*768

    hipMemsetAsync(flag, 0, (size_t)(64 + 3 * NN) * sizeof(int), stream);

    int eb = (EE + 255) / 256;  // 1250
    detect_k<<<eb, 256, 0, stream>>>(eidx, flag);
    convert_k<<<eb, 256, 0, stream>>>(eidx, flag, srcw, dstw);
    count_k<<<eb, 256, 0, stream>>>(srcw, dstw, deg_out, cnt_in);
    scan_k<<<1, 1024, 0, stream>>>(cnt_in, deg_out, row_ptr, disw);
    fill_k<<<eb, 256, 0, stream>>>(srcw, dstw, row_ptr, fillc, disw, colw, ww);

    cvt_k<<<MROWS * CC / 1024, 256, 0, stream>>>(feats, featsb);     // 40000 blocks
    wprep_k<<<(256 * 768 + 255) / 256, 256, 0, stream>>>(W, wcat);   // 768 blocks

    prop_k<<<NN, 256, 0, stream>>>(featsb, tx1b, row_ptr, colw, ww);
    prop_k<<<NN, 256, 0, stream>>>(tx1b, p2b, row_ptr, colw, ww);

    // fused GEMM + bias + LayerNorm (layer-1 params; layer-0 output is overwritten)
    gemmln_k<<<MROWS / 128, 512, 0, stream>>>(featsb, tx1b, p2b, wcat,
                                              bvec + CC, lnw + CC, lnb + CC, outp);
}

// Round 4
// 907.530 us; speedup vs baseline: 1.0712x; 1.0077x over previous
//
#include <hip/hip_runtime.h>
#include <stdint.h>

// Problem constants (fixed by reference)
#define BB 8
#define NN 20000
#define CC 256
#define EE 320000
#define KK 3
#define MROWS (BB * NN)   // 160000
#define ROWU (BB * CC)    // 2048 ushorts per node-group (4 KB)

// ---------- bf16 helpers (raw ushort representation) ----------
__device__ __forceinline__ float bf2f(ushort u) {
    union { uint32_t ui; float f; } v; v.ui = ((uint32_t)u) << 16; return v.f;
}
__device__ __forceinline__ ushort f2bf(float f) {
    union { uint32_t ui; float f; } v; v.f = f;
    uint32_t r = (v.ui + 0x7FFFu + ((v.ui >> 16) & 1u)) >> 16;
    return (ushort)r;
}

typedef __bf16 bf16x8 __attribute__((ext_vector_type(8)));
typedef float  f32x4  __attribute__((ext_vector_type(4)));

__device__ __forceinline__ void gload16(const void* gptr, void* lptr) {
    __builtin_amdgcn_global_load_lds(
        (const __attribute__((address_space(1))) void*)gptr,
        (__attribute__((address_space(3))) void*)lptr, 16, 0, 0);
}

// ---------- edge width detect (FALLBACK ONLY when in_sizes is ambiguous) ----------
__global__ void detect_k(const int* __restrict__ raw, int* __restrict__ flag) {
    int i = blockIdx.x * 256 + threadIdx.x;
    int v = 0;
    int idx = 2 * i + 1;
    if (i < EE) v = raw[idx];            // odd 32-bit word in [0, 2E)
    unsigned long long m = __ballot(v != 0);
    if ((threadIdx.x & 63) == 0 && m) atomicOr(flag, 1);
}

// fused: normalize edges to int32 src[]/dst[] + degree counts (one pass)
// mode: 1 = int32, 2 = int64, 0 = read flag (device-detected fallback)
__global__ void convcount_k(const int* __restrict__ raw, const int* __restrict__ flag,
                            int mode,
                            int* __restrict__ src, int* __restrict__ dst,
                            int* __restrict__ deg_out, int* __restrict__ cnt_in) {
    int e = blockIdx.x * 256 + threadIdx.x;
    if (e >= EE) return;
    int m = mode ? mode : (*flag ? 1 : 2);   // flag!=0 -> genuine int32 data
    int s, d;
    if (m == 2) { s = raw[2 * e]; d = raw[2 * EE + 2 * e]; }   // int64 low words
    else        { s = raw[e];     d = raw[EE + e]; }            // int32
    src[e] = s; dst[e] = d;
    atomicAdd(&deg_out[s], 1);
    atomicAdd(&cnt_in[d], 1);
}

// single-block scan, shfl-based: thread t owns 20 contiguous elements.
__global__ void __launch_bounds__(1024) scan_k(const int* __restrict__ cnt_in,
                                               const int* __restrict__ deg_out,
                                               int* __restrict__ row_ptr,
                                               float* __restrict__ dis) {
    __shared__ int wpart[16];
    const int t = threadIdx.x;
    const int lane = t & 63, wid = t >> 6;
    const int base = t * 20;
    int local[20];
    int sum = 0;
#pragma unroll
    for (int i = 0; i < 20; i++) {
        int idx = base + i;
        int v = (idx < NN) ? cnt_in[idx] : 0;
        local[i] = sum;
        sum += v;
    }
    int sc = sum;  // inclusive wave scan of per-thread sums
#pragma unroll
    for (int off = 1; off < 64; off <<= 1) {
        int u = __shfl_up(sc, off, 64);
        if (lane >= off) sc += u;
    }
    if (lane == 63) wpart[wid] = sc;
    __syncthreads();
    if (wid == 0 && lane < 16) {
        int v = wpart[lane];
#pragma unroll
        for (int off = 1; off < 16; off <<= 1) {
            int u = __shfl_up(v, off, 64);
            if (lane >= off) v += u;
        }
        wpart[lane] = v;
    }
    __syncthreads();
    int wbase = (wid > 0) ? wpart[wid - 1] : 0;
    int tbase = wbase + sc - sum;  // exclusive base for this thread
#pragma unroll
    for (int i = 0; i < 20; i++) {
        int idx = base + i;
        if (idx < NN) row_ptr[idx] = tbase + local[i];
    }
    if (t == 1023) row_ptr[NN] = tbase + sum;
    for (int i = t; i < NN; i += 1024) {
        int d = deg_out[i];
        dis[i] = (d > 0) ? rsqrtf((float)d) : 0.0f;
    }
}

__global__ void fill_k(const int* __restrict__ src, const int* __restrict__ dst,
                       const int* __restrict__ row_ptr, int* __restrict__ fillc,
                       const float* __restrict__ dis,
                       int* __restrict__ col, float* __restrict__ w) {
    int e = blockIdx.x * 256 + threadIdx.x;
    if (e >= EE) return;
    int s = src[e], d = dst[e];
    int pos = row_ptr[d] + atomicAdd(&fillc[d], 1);
    col[pos] = s;
    w[pos] = -dis[s] * dis[d];
}

// fused: fp32 [b,n,c] -> bf16 node-major [n,b,c]  (blocks 0..39999)
//      + WcatT prep                               (blocks 40000..40767)
// WcatT[n][k] bf16, n in [0,256), k in [0,768):
//   block 0: W1[0]-W1[2], block 1: W1[1], block 2: 2*W1[2]   (Tx2 = 2*P2 - Tx0 folded)
__global__ void cvtwprep_k(const float* __restrict__ x, ushort* __restrict__ y,
                           const float* __restrict__ W, ushort* __restrict__ wt) {
    int bid = blockIdx.x;
    if (bid < MROWS * CC / 1024) {
        size_t idx = ((size_t)bid * 256 + threadIdx.x) * 4;
        int row = (int)(idx >> 8);     // b*N + n  (< 160000)
        int c = (int)(idx & 255);
        int b = row / NN, n = row - b * NN;
        float4 v = *(const float4*)(x + idx);
        ushort4 o = make_ushort4(f2bf(v.x), f2bf(v.y), f2bf(v.z), f2bf(v.w));
        *(ushort4*)(y + ((size_t)(n * BB + b) * CC + c)) = o;
    } else {
        int idx = (bid - MROWS * CC / 1024) * 256 + threadIdx.x;
        if (idx >= 256 * 768) return;
        int n = idx / 768, k = idx % 768;
        int sel = k >> 8, kk = k & 255;
        const float* W1 = W + KK * CC * CC;  // layer 1
        float v;
        if (sel == 0)      v = W1[kk * CC + n] - W1[2 * CC * CC + kk * CC + n];
        else if (sel == 1) v = W1[CC * CC + kk * CC + n];
        else               v = 2.0f * W1[2 * CC * CC + kk * CC + n];
        wt[idx] = f2bf(v);
    }
}

// Node-major prop: y[n, :, :] = sum_{e: dst=n} w[e] * x[col[e], :, :]
// one 256-thread block per dst node; thread t covers bytes [t*16, t*16+16)
// of the 4 KB node-group. Edge loop unrolled by 4 for MLP.
// (unroll-8 measured NULL: same 196 us at occupancy 52% vs 70% -> fetch-path wall,
//  not ILP/occupancy. Keep the 24-VGPR unroll-4 form.)
__global__ void __launch_bounds__(256) prop_k(const ushort* __restrict__ x,
                                              ushort* __restrict__ y,
                                              const int* __restrict__ row_ptr,
                                              const int* __restrict__ col,
                                              const float* __restrict__ w) {
    const int n = blockIdx.x;
    const int t = threadIdx.x;
    const int beg = row_ptr[n], end = row_ptr[n + 1];
    const ushort* xb = x + t * 8;   // 8 ushorts = 16 B per thread
    float a0 = 0, a1 = 0, a2 = 0, a3 = 0, a4 = 0, a5 = 0, a6 = 0, a7 = 0;
    int j = beg;
    for (; j + 4 <= end; j += 4) {
        int s0 = col[j], s1 = col[j + 1], s2 = col[j + 2], s3 = col[j + 3];
        float w0 = w[j], w1 = w[j + 1], w2 = w[j + 2], w3 = w[j + 3];
        uint4 v0 = *(const uint4*)(xb + (size_t)s0 * ROWU);
        uint4 v1 = *(const uint4*)(xb + (size_t)s1 * ROWU);
        uint4 v2 = *(const uint4*)(xb + (size_t)s2 * ROWU);
        uint4 v3 = *(const uint4*)(xb + (size_t)s3 * ROWU);
        a0 += w0 * bf2f((ushort)v0.x) + w1 * bf2f((ushort)v1.x) + w2 * bf2f((ushort)v2.x) + w3 * bf2f((ushort)v3.x);
        a1 += w0 * bf2f((ushort)(v0.x >> 16)) + w1 * bf2f((ushort)(v1.x >> 16)) + w2 * bf2f((ushort)(v2.x >> 16)) + w3 * bf2f((ushort)(v3.x >> 16));
        a2 += w0 * bf2f((ushort)v0.y) + w1 * bf2f((ushort)v1.y) + w2 * bf2f((ushort)v2.y) + w3 * bf2f((ushort)v3.y);
        a3 += w0 * bf2f((ushort)(v0.y >> 16)) + w1 * bf2f((ushort)(v1.y >> 16)) + w2 * bf2f((ushort)(v2.y >> 16)) + w3 * bf2f((ushort)(v3.y >> 16));
        a4 += w0 * bf2f((ushort)v0.z) + w1 * bf2f((ushort)v1.z) + w2 * bf2f((ushort)v2.z) + w3 * bf2f((ushort)v3.z);
        a5 += w0 * bf2f((ushort)(v0.z >> 16)) + w1 * bf2f((ushort)(v1.z >> 16)) + w2 * bf2f((ushort)(v2.z >> 16)) + w3 * bf2f((ushort)(v3.z >> 16));
        a6 += w0 * bf2f((ushort)v0.w) + w1 * bf2f((ushort)v1.w) + w2 * bf2f((ushort)v2.w) + w3 * bf2f((ushort)v3.w);
        a7 += w0 * bf2f((ushort)(v0.w >> 16)) + w1 * bf2f((ushort)(v1.w >> 16)) + w2 * bf2f((ushort)(v2.w >> 16)) + w3 * bf2f((ushort)(v3.w >> 16));
    }
    for (; j < end; j++) {
        int s = col[j];
        float wt = w[j];
        uint4 v = *(const uint4*)(xb + (size_t)s * ROWU);
        a0 += wt * bf2f((ushort)v.x);
        a1 += wt * bf2f((ushort)(v.x >> 16));
        a2 += wt * bf2f((ushort)v.y);
        a3 += wt * bf2f((ushort)(v.y >> 16));
        a4 += wt * bf2f((ushort)v.z);
        a5 += wt * bf2f((ushort)(v.z >> 16));
        a6 += wt * bf2f((ushort)v.w);
        a7 += wt * bf2f((ushort)(v.w >> 16));
    }
    uint4 o;
    o.x = (uint32_t)f2bf(a0) | ((uint32_t)f2bf(a1) << 16);
    o.y = (uint32_t)f2bf(a2) | ((uint32_t)f2bf(a3) << 16);
    o.z = (uint32_t)f2bf(a4) | ((uint32_t)f2bf(a5) << 16);
    o.w = (uint32_t)f2bf(a6) | ((uint32_t)f2bf(a7) << 16);
    *(uint4*)(y + (size_t)n * ROWU + t * 8) = o;
}

// Fused GEMM + bias + LayerNorm.
// out = [A0|A1|A2] (bf16, node-major rows m'=n*8+b) @ WcatT^T, then per-row LN,
// with row un-permutation (m' -> b*N+n) in the epilogue.
// Tile: 128 rows x 256 cols (full C width -> row stats in-block), BK=64 (12 K-steps,
// half the barrier drains of BK=32), 512 threads = 8 waves (2x4), wave tile 64x64.
// LDS XOR-swizzle (T2): 128 B rows would be a 16-way read conflict; physical chunk
// p holds logical chunk p^(row&7). gload_lds dest stays LINEAR; the GLOBAL source
// address is pre-swizzled (rule #21 / m173 pattern); reads apply the same XOR ->
// 2-way (free, m136).
__global__ void __launch_bounds__(512, 4) gemmln_k(const ushort* __restrict__ a0,
                                                   const ushort* __restrict__ a1,
                                                   const ushort* __restrict__ a2,
                                                   const ushort* __restrict__ wt,
                                                   const float* __restrict__ bias,
                                                   const float* __restrict__ lnw,
                                                   const float* __restrict__ lnb,
                                                   float* __restrict__ out) {
    __shared__ ushort As[128 * 64];   // 16 KB
    __shared__ ushort Bs[256 * 64];   // 32 KB
    __shared__ float reds[128][4];    // per-row per-colwave partial sum
    __shared__ float redq[128][4];    // per-row per-colwave partial sumsq
    const int tid = threadIdx.x;
    const int wid = tid >> 6, lane = tid & 63;
    const int wrow = wid >> 2, wcol = wid & 3;
    const int quad = lane >> 4, l16 = lane & 15;
    const int row0 = blockIdx.x * 128;

    f32x4 acc[4][4] = {};

    for (int kt = 0; kt < 12; kt++) {
        const ushort* ab = (kt < 4) ? a0 : ((kt < 8) ? a1 : a2);
        const int kl = (kt & 3) * 64;        // k offset within the 256-col A buffer
        const int kg = kt * 64;              // global k for WcatT
        __syncthreads();
        // stage A: 128x64 bf16 = 16 KB = 1024 chunks of 16 B; chunk c = q2*512+tid
        // physical chunk (m, p) <- global logical chunk p^(m&7)
#pragma unroll
        for (int q2 = 0; q2 < 2; q2++) {
            int c = q2 * 512 + tid;
            int m = c >> 3, p = c & 7;
            int kq = (p ^ (m & 7)) * 8;
            gload16(ab + (size_t)(row0 + m) * CC + kl + kq,
                    &As[(q2 * 512 + wid * 64) * 8]);
        }
        // stage B: 256x64 bf16 = 32 KB = 2048 chunks
#pragma unroll
        for (int q2 = 0; q2 < 4; q2++) {
            int c = q2 * 512 + tid;
            int m = c >> 3, p = c & 7;
            int kq = (p ^ (m & 7)) * 8;
            gload16(wt + (size_t)m * 768 + kg + kq,
                    &Bs[(q2 * 512 + wid * 64) * 8]);
        }
        __syncthreads();

#pragma unroll
        for (int ks = 0; ks < 2; ks++) {
            bf16x8 af[4], bfr[4];
#pragma unroll
            for (int mt = 0; mt < 4; mt++) {
                int r = wrow * 64 + mt * 16 + l16;
                int pc = (ks * 4 + quad) ^ (r & 7);
                af[mt] = *(const bf16x8*)&As[r * 64 + pc * 8];
            }
#pragma unroll
            for (int nt = 0; nt < 4; nt++) {
                int r = wcol * 64 + nt * 16 + l16;
                int pc = (ks * 4 + quad) ^ (r & 7);
                bfr[nt] = *(const bf16x8*)&Bs[r * 64 + pc * 8];
            }
#pragma unroll
            for (int mt = 0; mt < 4; mt++)
#pragma unroll
                for (int nt = 0; nt < 4; nt++)
                    acc[mt][nt] = __builtin_amdgcn_mfma_f32_16x16x32_bf16(
                        af[mt], bfr[nt], acc[mt][nt], 0, 0, 0);
        }
    }

    // ---- fused epilogue: bias + LayerNorm + un-permute + store ----
    // C/D layout: col = lane&15, row = (lane>>4)*4 + reg   [measured m89]
    // lane's cols: wcol*64 + nt*16 + l16, nt=0..3
    float bv[4], lwv[4], lbv[4];
#pragma unroll
    for (int nt = 0; nt < 4; nt++) {
        int c = wcol * 64 + nt * 16 + l16;
        bv[nt] = bias[c]; lwv[nt] = lnw[c]; lbv[nt] = lnb[c];
    }
    // per-row partial stats over this wave's 64 cols (reduce over l16 group)
#pragma unroll
    for (int mt = 0; mt < 4; mt++) {
#pragma unroll
        for (int r = 0; r < 4; r++) {
            float s = 0.0f, q = 0.0f;
#pragma unroll
            for (int nt = 0; nt < 4; nt++) {
                float v = acc[mt][nt][r] + bv[nt];
                s += v; q += v * v;
            }
#pragma unroll
            for (int off = 1; off < 16; off <<= 1) {
                s += __shfl_xor(s, off, 64);
                q += __shfl_xor(q, off, 64);
            }
            if (l16 == 0) {
                int ml = wrow * 64 + mt * 16 + quad * 4 + r;
                reds[ml][wcol] = s;
                redq[ml][wcol] = q;
            }
        }
    }
    __syncthreads();
#pragma unroll
    for (int mt = 0; mt < 4; mt++) {
#pragma unroll
        for (int r = 0; r < 4; r++) {
            int ml = wrow * 64 + mt * 16 + quad * 4 + r;
            float s = reds[ml][0] + reds[ml][1] + reds[ml][2] + reds[ml][3];
            float q = redq[ml][0] + redq[ml][1] + redq[ml][2] + redq[ml][3];
            float mean = s * (1.0f / CC);
            float var = q * (1.0f / CC) - mean * mean;
            float rs = rsqrtf(var + 1e-5f);
            int m = row0 + ml;
            int n = m >> 3, b = m & 7;
            size_t orow = (size_t)b * NN + n;
#pragma unroll
            for (int nt = 0; nt < 4; nt++) {
                int c = wcol * 64 + nt * 16 + l16;
                float v = (acc[mt][nt][r] + bv[nt] - mean) * rs * lwv[nt] + lbv[nt];
                out[orow * CC + c] = v;
            }
        }
    }
}

extern "C" void kernel_launch(void* const* d_in, const int* in_sizes, int n_in,
                              void* d_out, int out_size, void* d_ws, size_t ws_size,
                              hipStream_t stream) {
    const float* feats = (const float*)d_in[0];
    const float* W     = (const float*)d_in[1];   // [L,K,C,C]
    const float* bvec  = (const float*)d_in[2];   // [L,C]
    const float* lnw   = (const float*)d_in[3];   // [L,C]
    const float* lnb   = (const float*)d_in[4];   // [L,C]
    const int*   eidx  = (const int*)d_in[5];     // (2,E) int32 or int64 (detected)
    float* outp = (float*)d_out;

    // ---- workspace carve-up ----
    int* flag    = (int*)d_ws;            // 64 ints (only [0] used)
    int* deg_out = flag + 64;             // N
    int* cnt_in  = deg_out + NN;          // N
    int* fillc   = cnt_in + NN;           // N   (memset covers up to here)
    int* row_ptr = fillc + NN;            // N+1 (+pad)
    int* srcw    = row_ptr + (NN + 64);   // E
    int* dstw    = srcw + EE;             // E
    int* colw    = dstw + EE;             // E
    float* disw  = (float*)(colw + EE);   // N (+pad)
    float* ww    = disw + (NN + 64);      // E
    uintptr_t bf_base = ((uintptr_t)(ww + EE) + 255) & ~(uintptr_t)255;
    ushort* featsb = (ushort*)bf_base;                 // M*C bf16  [n,b,c]
    ushort* tx1b   = featsb + (size_t)MROWS * CC;      // M*C
    ushort* p2b    = tx1b + (size_t)MROWS * CC;        // M*C
    ushort* wcat   = p2b + (size_t)MROWS * CC;         // 256*768

    hipMemsetAsync(flag, 0, (size_t)(64 + 3 * NN) * sizeof(int), stream);

    // host-side edge width detection from input byte size; device fallback if ambiguous
    int mode = 0;
    long long esz = in_sizes ? (long long)in_sizes[5] : 0;
    if (esz == (long long)2 * EE * 8) mode = 2;        // int64
    else if (esz == (long long)2 * EE * 4) mode = 1;   // int32

    int eb = (EE + 255) / 256;  // 1250
    if (mode == 0) detect_k<<<eb, 256, 0, stream>>>(eidx, flag);
    convcount_k<<<eb, 256, 0, stream>>>(eidx, flag, mode, srcw, dstw, deg_out, cnt_in);
    scan_k<<<1, 1024, 0, stream>>>(cnt_in, deg_out, row_ptr, disw);
    fill_k<<<eb, 256, 0, stream>>>(srcw, dstw, row_ptr, fillc, disw, colw, ww);

    cvtwprep_k<<<MROWS * CC / 1024 + 768, 256, 0, stream>>>(feats, featsb, W, wcat);

    prop_k<<<NN, 256, 0, stream>>>(featsb, tx1b, row_ptr, colw, ww);
    prop_k<<<NN, 256, 0, stream>>>(tx1b, p2b, row_ptr, colw, ww);

    // fused GEMM + bias + LayerNorm (layer-1 params; layer-0 output is overwritten)
    gemmln_k<<<MROWS / 128, 512, 0, stream>>>(featsb, tx1b, p2b, wcat,
                                              bvec + CC, lnw + CC, lnb + CC, outp);
}